// Round 1
// baseline (767.009 us; speedup 1.0000x reference)
//
#include <hip/hip_runtime.h>
#include <hip/hip_bf16.h>

#define LOG_2PI 1.8378770664093453f

// ---------------------------------------------------------------------------
// Kernel 1a: build A (512x512): strict-lower from lower_tri (row-major
// tril_indices order: row i holds cols 0..i-1 at flat i*(i-1)/2 + j),
// diag = exp(log_diagonal), upper = 0.
// ---------------------------------------------------------------------------
__global__ __launch_bounds__(256) void build_A(const float* __restrict__ logd,
                                               const float* __restrict__ lt,
                                               float* __restrict__ A) {
    int idx = blockIdx.x * 256 + threadIdx.x;   // grid 1024 -> 262144 = 512*512
    int i = idx >> 9, j = idx & 511;
    float v;
    if (j < i)       v = lt[(i * (i - 1)) / 2 + j];
    else if (j == i) v = expf(logd[i]);
    else             v = 0.f;
    A[idx] = v;
}

// ---------------------------------------------------------------------------
// Kernel 1b: cov = A * A^T  (512x512). 32x32 tiles, 256 threads/block.
// ---------------------------------------------------------------------------
__global__ __launch_bounds__(256) void aat(const float* __restrict__ A,
                                           float* __restrict__ C) {
    __shared__ float Ash[32][33];
    __shared__ float Bsh[32][33];
    int tx = threadIdx.x & 31, ty = threadIdx.x >> 5;   // tx 0..31, ty 0..7
    int bi = blockIdx.y, bj = blockIdx.x;
    float acc[4] = {0.f, 0.f, 0.f, 0.f};
    for (int k0 = 0; k0 < 512; k0 += 32) {
        #pragma unroll
        for (int q = 0; q < 4; q++) {
            int r = ty + q * 8;
            Ash[r][tx] = A[(bi * 32 + r) * 512 + k0 + tx];
            Bsh[r][tx] = A[(bj * 32 + r) * 512 + k0 + tx];
        }
        __syncthreads();
        for (int c = 0; c < 32; c++) {
            float bv = Bsh[tx][c];
            #pragma unroll
            for (int q = 0; q < 4; q++) acc[q] += Ash[ty + q * 8][c] * bv;
        }
        __syncthreads();
    }
    #pragma unroll
    for (int q = 0; q < 4; q++)
        C[(bi * 32 + ty + q * 8) * 512 + bj * 32 + tx] = acc[q];
}

// ---------------------------------------------------------------------------
// Kernel 2: per-sample mask compaction. One block (256 thr) per sample.
// Produces obs_idx[b][*] (ascending), n_obs[b], compact residual rc[b][*].
// ---------------------------------------------------------------------------
__global__ __launch_bounds__(256) void compact(const float* __restrict__ x,
                                               const float* __restrict__ mu,
                                               const int* __restrict__ mask,
                                               int* __restrict__ obs_idx,
                                               int* __restrict__ n_obs,
                                               float* __restrict__ rc) {
    int b = blockIdx.x, t = threadIdx.x;
    __shared__ int wsum[4];
    int i0 = 2 * t, i1 = 2 * t + 1;
    int m0 = (mask[b * 512 + i0] != 0) ? 1 : 0;
    int m1 = (mask[b * 512 + i1] != 0) ? 1 : 0;
    int local = m0 + m1;
    int v = local;
    int lane = t & 63, wv = t >> 6;
    #pragma unroll
    for (int off = 1; off < 64; off <<= 1) {
        int u = __shfl_up(v, off, 64);
        if (lane >= off) v += u;
    }
    if (lane == 63) wsum[wv] = v;
    __syncthreads();
    int woff = 0;
    for (int w = 0; w < wv; w++) woff += wsum[w];
    int excl = woff + v - local;   // exclusive prefix at element i0
    if (m0) { obs_idx[b * 512 + excl] = i0; rc[b * 512 + excl] = x[b * 512 + i0] - mu[i0]; }
    if (m1) { int p = excl + m0; obs_idx[b * 512 + p] = i1; rc[b * 512 + p] = x[b * 512 + i1] - mu[i1]; }
    if (t == 0) n_obs[b] = wsum[0] + wsum[1] + wsum[2] + wsum[3];
}

// ---------------------------------------------------------------------------
// Kernel 3: gather per-sample compact submatrix (lower triangle only):
// S[i][j] = cov[obs_i][obs_j], j <= i.  One block per sample in the chunk.
// ---------------------------------------------------------------------------
__global__ __launch_bounds__(256) void gather_S(const float* __restrict__ cov,
                                                const int* __restrict__ obs_idx,
                                                const int* __restrict__ n_obs,
                                                float* __restrict__ S,
                                                int c0, int lda) {
    int b = c0 + blockIdx.x;
    int n = n_obs[b]; if (n > lda) n = lda;
    __shared__ int oi[512];
    for (int i = threadIdx.x; i < n; i += 256) oi[i] = obs_idx[b * 512 + i];
    __syncthreads();
    float* Sb = S + (size_t)blockIdx.x * lda * lda;
    for (int i = 0; i < n; i++) {
        const float* crow = cov + (size_t)oi[i] * 512;
        for (int j = threadIdx.x; j <= i; j += 256)
            Sb[(size_t)i * lda + j] = crow[oi[j]];
    }
}

// ---------------------------------------------------------------------------
// Kernel 4: per-sample blocked Cholesky (NB=32, panel in LDS) + forward
// solve + quad/logdet reduction -> out[b]. One 256-thread block per sample.
// ---------------------------------------------------------------------------
__global__ __launch_bounds__(256) void chol_solve(const float* __restrict__ rc,
                                                  const int* __restrict__ n_obs,
                                                  float* __restrict__ S,
                                                  float* __restrict__ out,
                                                  int c0, int lda) {
    int b = c0 + blockIdx.x;
    int tid = threadIdx.x;
    int n = n_obs[b]; if (n > lda) n = lda;
    float* Sb = S + (size_t)blockIdx.x * lda * lda;

    __shared__ __align__(16) float P[388 * 36];   // panel: rows x 32 (stride 36, 16B-aligned rows)
    __shared__ float zsh[384];
    __shared__ float diagbuf[32];
    __shared__ float redbuf[8];

    if (n == 0) { if (tid == 0) out[b] = 0.f; return; }

    // ---------------- factorization ----------------
    for (int j0 = 0; j0 < n; j0 += 32) {
        int nb = min(32, n - j0);
        int h = n - j0;
        // load panel (cols j0..j0+nb) into LDS; zero unused cols
        for (int e = tid; e < h * 32; e += 256) {
            int r = e >> 5, c = e & 31;
            P[r * 36 + c] = (c < nb) ? Sb[(size_t)(j0 + r) * lda + j0 + c] : 0.f;
        }
        // zero-pad 4 extra rows for 4x4 syrk tiles
        if (tid < 128) { int r = h + (tid >> 5), c = tid & 31; P[r * 36 + c] = 0.f; }
        __syncthreads();

        // combined diag factor + panel trsm (unblocked over k)
        for (int k = 0; k < nb; k++) {
            float dkk = P[k * 36 + k];          // safe: only rank-1 of step k-1 wrote it (sync'd)
            float lkk = sqrtf(dkk);
            float rinv = 1.f / lkk;
            if (tid == 0) diagbuf[k] = lkk;     // deferred diag write (avoids RAW race on P[k][k])
            for (int r = k + 1 + tid; r < h; r += 256) P[r * 36 + k] *= rinv;
            __syncthreads();
            for (int r = k + 1 + tid; r < h; r += 256) {
                float pk = P[r * 36 + k];
                for (int j = k + 1; j < nb; j++) P[r * 36 + j] -= pk * P[j * 36 + k];
            }
            __syncthreads();
        }

        // write back panel (diag from diagbuf)
        for (int e = tid; e < h * 32; e += 256) {
            int r = e >> 5, c = e & 31;
            if (c < nb)
                Sb[(size_t)(j0 + r) * lda + j0 + c] = (r == c) ? diagbuf[r] : P[r * 36 + c];
        }

        // trailing syrk: S[i][j] -= dot(P[i-j0], P[j-j0]) over 32 k's, 4x4 tiles
        int m = n - (j0 + nb);
        if (m > 0) {
            int T = (m + 3) >> 2;
            int ntiles = T * (T + 1) / 2;
            for (int e = tid; e < ntiles; e += 256) {
                int ti = (int)((sqrtf(8.f * (float)e + 1.f) - 1.f) * 0.5f);
                while ((ti + 1) * (ti + 2) / 2 <= e) ti++;
                while (ti * (ti + 1) / 2 > e) ti--;
                int tj = e - ti * (ti + 1) / 2;
                int ibase = j0 + nb + ti * 4, jbase = j0 + nb + tj * 4;
                int pi = nb + ti * 4, pj = nb + tj * 4;
                float acc[4][4] = {{0.f}};
                for (int k = 0; k < 32; k += 4) {
                    float4 av[4], bv[4];
                    #pragma unroll
                    for (int a = 0; a < 4; a++) av[a] = *(const float4*)&P[(pi + a) * 36 + k];
                    #pragma unroll
                    for (int a = 0; a < 4; a++) bv[a] = *(const float4*)&P[(pj + a) * 36 + k];
                    #pragma unroll
                    for (int a = 0; a < 4; a++)
                        #pragma unroll
                        for (int c = 0; c < 4; c++)
                            acc[a][c] += av[a].x * bv[c].x + av[a].y * bv[c].y +
                                         av[a].z * bv[c].z + av[a].w * bv[c].w;
                }
                #pragma unroll
                for (int a = 0; a < 4; a++) {
                    int i = ibase + a;
                    if (i < n) {
                        #pragma unroll
                        for (int c = 0; c < 4; c++) {
                            int j = jbase + c;
                            if (j < n && j <= i) Sb[(size_t)i * lda + j] -= acc[a][c];
                        }
                    }
                }
            }
        }
        __syncthreads();   // protect P before next panel load
    }

    // ---------------- logdet partial ----------------
    float lsum = 0.f;
    for (int i = tid; i < n; i += 256) lsum += logf(Sb[(size_t)i * lda + i]);

    // ---------------- forward solve L z = r ----------------
    for (int i = tid; i < n; i += 256) zsh[i] = rc[b * 512 + i];
    __syncthreads();
    for (int j0 = 0; j0 < n; j0 += 32) {
        int nb = min(32, n - j0);
        if (tid < 64) {
            int l = tid;
            bool act = (l < nb);
            float Lr[32];
            float z = 0.f;
            if (act) {
                const float* rowp = Sb + (size_t)(j0 + l) * lda + j0;
                #pragma unroll
                for (int c = 0; c < 32; c++) Lr[c] = (c <= l) ? rowp[c] : 0.f;
                z = zsh[j0 + l];
            } else {
                #pragma unroll
                for (int c = 0; c < 32; c++) Lr[c] = 0.f;
            }
            #pragma unroll
            for (int k = 0; k < 32; k++) {
                if (k < nb) {                    // wave-uniform
                    if (l == k) z = z / Lr[k];
                    float zk = __shfl(z, k, 64);
                    if (act && l > k) z -= Lr[k] * zk;
                }
            }
            if (act) zsh[j0 + l] = z;
        }
        __syncthreads();
        // update remaining rows: z[i] -= L[i][j0:j0+nb] . z[j0:j0+nb]
        for (int i = j0 + nb + tid; i < n; i += 256) {
            const float* row = Sb + (size_t)i * lda + j0;
            float s = 0.f;
            for (int c = 0; c < nb; c++) s += row[c] * zsh[j0 + c];
            zsh[i] -= s;
        }
        __syncthreads();
    }

    // ---------------- quad + reduce + output ----------------
    float q = 0.f;
    for (int i = tid; i < n; i += 256) { float z = zsh[i]; q += z * z; }
    #pragma unroll
    for (int off = 32; off; off >>= 1) {
        q    += __shfl_down(q, off, 64);
        lsum += __shfl_down(lsum, off, 64);
    }
    int lane = tid & 63, wv = tid >> 6;
    if (lane == 0) { redbuf[wv] = q; redbuf[4 + wv] = lsum; }
    __syncthreads();
    if (tid == 0) {
        float qt = redbuf[0] + redbuf[1] + redbuf[2] + redbuf[3];
        float ls = redbuf[4] + redbuf[5] + redbuf[6] + redbuf[7];
        out[b] = 0.5f * (qt + 2.f * ls + (float)n * LOG_2PI);
    }
}

// ---------------------------------------------------------------------------
// Launcher. ws layout (bytes):
//   [0, 1MB)        cov (512*512 f32)
//   [1MB, 2MB)      A   (512*512 f32)
//   [2MB, +1KB)     n_obs (256 i32)
//   [.., +512KB)    obs_idx (256*512 i32)
//   [.., +512KB)    rc (256*512 f32)
//   [3146752, ...)  S buffers: chunk * lda*lda f32 (chunked if ws is small)
// ---------------------------------------------------------------------------
extern "C" void kernel_launch(void* const* d_in, const int* in_sizes, int n_in,
                              void* d_out, int out_size, void* d_ws, size_t ws_size,
                              hipStream_t stream) {
    const float* x    = (const float*)d_in[0];
    const float* mu   = (const float*)d_in[1];
    const float* logd = (const float*)d_in[2];
    const float* lt   = (const float*)d_in[3];
    const int*   mask = (const int*)d_in[4];
    float* out = (float*)d_out;

    char* ws = (char*)d_ws;
    float* cov     = (float*)(ws);
    float* A       = (float*)(ws + 1048576);
    int*   n_obs   = (int*)  (ws + 2097152);
    int*   obs_idx = (int*)  (ws + 2098176);
    float* rc      = (float*)(ws + 2622464);
    float* S       = (float*)(ws + 3146752);

    const int lda = 384;
    size_t per = (size_t)lda * lda * 4;
    size_t avail = (ws_size > 3146752) ? (ws_size - 3146752) : 0;
    int chunk = (int)(avail / per);
    if (chunk > 256) chunk = 256;
    if (chunk < 1) chunk = 1;

    build_A<<<1024, 256, 0, stream>>>(logd, lt, A);
    dim3 g(16, 16);
    aat<<<g, 256, 0, stream>>>(A, cov);
    compact<<<256, 256, 0, stream>>>(x, mu, mask, obs_idx, n_obs, rc);

    for (int c0 = 0; c0 < 256; c0 += chunk) {
        int cn = (256 - c0 < chunk) ? (256 - c0) : chunk;
        gather_S<<<cn, 256, 0, stream>>>(cov, obs_idx, n_obs, S, c0, lda);
        chol_solve<<<cn, 256, 0, stream>>>(rc, n_obs, S, out, c0, lda);
    }
}

// Round 2
// 607.031 us; speedup vs baseline: 1.2635x; 1.2635x over previous
//
#include <hip/hip_runtime.h>
#include <hip/hip_bf16.h>

#define LOG_2PI 1.8378770664093453f
#define LDA 384
#define PROWS 392
#define PSTR 36   // floats per LDS panel row (32 data + 4 pad), 144B = 16B-aligned

// XOR swizzle of float4-chunks within a row: breaks the 8-row bank period.
__device__ __forceinline__ int psw(int r) { return (r ^ (r >> 3)) & 7; }

// ---------------------------------------------------------------------------
// build A: strict-lower from lower_tri, diag = exp(log_diagonal), upper 0.
// ---------------------------------------------------------------------------
__global__ __launch_bounds__(256) void build_A(const float* __restrict__ logd,
                                               const float* __restrict__ lt,
                                               float* __restrict__ A) {
    int idx = blockIdx.x * 256 + threadIdx.x;
    int i = idx >> 9, j = idx & 511;
    float v;
    if (j < i)       v = lt[(i * (i - 1)) / 2 + j];
    else if (j == i) v = expf(logd[i]);
    else             v = 0.f;
    A[idx] = v;
}

// ---------------------------------------------------------------------------
// cov = A * A^T (512x512), 32x32 tiles.
// ---------------------------------------------------------------------------
__global__ __launch_bounds__(256) void aat(const float* __restrict__ A,
                                           float* __restrict__ C) {
    __shared__ float Ash[32][33];
    __shared__ float Bsh[32][33];
    int tx = threadIdx.x & 31, ty = threadIdx.x >> 5;
    int bi = blockIdx.y, bj = blockIdx.x;
    float acc[4] = {0.f, 0.f, 0.f, 0.f};
    for (int k0 = 0; k0 < 512; k0 += 32) {
        #pragma unroll
        for (int q = 0; q < 4; q++) {
            int r = ty + q * 8;
            Ash[r][tx] = A[(bi * 32 + r) * 512 + k0 + tx];
            Bsh[r][tx] = A[(bj * 32 + r) * 512 + k0 + tx];
        }
        __syncthreads();
        for (int c = 0; c < 32; c++) {
            float bv = Bsh[tx][c];
            #pragma unroll
            for (int q = 0; q < 4; q++) acc[q] += Ash[ty + q * 8][c] * bv;
        }
        __syncthreads();
    }
    #pragma unroll
    for (int q = 0; q < 4; q++)
        C[(bi * 32 + ty + q * 8) * 512 + bj * 32 + tx] = acc[q];
}

// ---------------------------------------------------------------------------
// per-sample mask compaction -> obs_idx (ascending), n_obs, compact residual.
// ---------------------------------------------------------------------------
__global__ __launch_bounds__(256) void compact(const float* __restrict__ x,
                                               const float* __restrict__ mu,
                                               const int* __restrict__ mask,
                                               int* __restrict__ obs_idx,
                                               int* __restrict__ n_obs,
                                               float* __restrict__ rc) {
    int b = blockIdx.x, t = threadIdx.x;
    __shared__ int wsum[4];
    int i0 = 2 * t, i1 = 2 * t + 1;
    int m0 = (mask[b * 512 + i0] != 0) ? 1 : 0;
    int m1 = (mask[b * 512 + i1] != 0) ? 1 : 0;
    int local = m0 + m1;
    int v = local;
    int lane = t & 63, wv = t >> 6;
    #pragma unroll
    for (int off = 1; off < 64; off <<= 1) {
        int u = __shfl_up(v, off, 64);
        if (lane >= off) v += u;
    }
    if (lane == 63) wsum[wv] = v;
    __syncthreads();
    int woff = 0;
    for (int w = 0; w < wv; w++) woff += wsum[w];
    int excl = woff + v - local;
    if (m0) { obs_idx[b * 512 + excl] = i0; rc[b * 512 + excl] = x[b * 512 + i0] - mu[i0]; }
    if (m1) { int p = excl + m0; obs_idx[b * 512 + p] = i1; rc[b * 512 + p] = x[b * 512 + i1] - mu[i1]; }
    if (t == 0) n_obs[b] = wsum[0] + wsum[1] + wsum[2] + wsum[3];
}

// ---------------------------------------------------------------------------
// Fused gather + blocked Cholesky + forward solve + NLL. 1 block = 1 sample.
// Sb holds ONLY accumulated syrk updates (panel0 writes = -acc).
// L panels live in LDS only; z solved panel-by-panel; 4 barriers/panel.
// ---------------------------------------------------------------------------
__global__ __launch_bounds__(256, 1) void chol_solve(
    const float* __restrict__ cov, const float* __restrict__ rc,
    const int* __restrict__ obs_idx, const int* __restrict__ n_obs,
    float* __restrict__ S, float* __restrict__ out, int c0) {
    int b = c0 + blockIdx.x;
    int tid = threadIdx.x;
    int n = n_obs[b]; if (n > LDA) n = LDA;
    float* Sb = S + (size_t)blockIdx.x * LDA * LDA;

    __shared__ __align__(16) float P[PROWS * PSTR];
    __shared__ float zsh[LDA];
    __shared__ int   oi[LDA];
    __shared__ float dinvbuf[32];
    __shared__ float redbuf[8];

    if (n == 0) { if (tid == 0) out[b] = 0.f; return; }

    for (int i = tid; i < n; i += 256) {
        oi[i] = obs_idx[b * 512 + i];
        zsh[i] = rc[b * 512 + i];
    }
    __syncthreads();

    float llog = 0.f;   // only wave0 lanes <32 accumulate

    for (int j0 = 0; j0 < n; j0 += 32) {
        int nb = min(32, n - j0);
        int h = n - j0;
        int m = h - nb;             // m>0 implies nb==32
        bool first = (j0 == 0);

        // ---------------- load panel: gather(cov) + Sb accum ----------------
        for (int r = tid; r < h; r += 256) {
            const float* crow = cov + (size_t)oi[j0 + r] * 512;
            const float* srow = Sb + (size_t)(j0 + r) * LDA + j0;
            float* prow = P + r * PSTR;
            int sw = psw(r);
            #pragma unroll
            for (int q = 0; q < 8; q++) {
                float4 v;
                if (4 * q < nb) {
                    v.x = crow[oi[j0 + 4 * q + 0]];
                    v.y = (4 * q + 1 < nb) ? crow[oi[j0 + 4 * q + 1]] : 0.f;
                    v.z = (4 * q + 2 < nb) ? crow[oi[j0 + 4 * q + 2]] : 0.f;
                    v.w = (4 * q + 3 < nb) ? crow[oi[j0 + 4 * q + 3]] : 0.f;
                    if (!first) {
                        float4 s4 = *(const float4*)(srow + 4 * q);
                        v.x += s4.x;
                        if (4 * q + 1 < nb) v.y += s4.y;
                        if (4 * q + 2 < nb) v.z += s4.z;
                        if (4 * q + 3 < nb) v.w += s4.w;
                    }
                } else {
                    v = make_float4(0.f, 0.f, 0.f, 0.f);
                }
                *(float4*)(prow + ((q ^ sw) << 2)) = v;
            }
        }
        // zero-pad rows h..h+7 (exactly 256 elements)
        {
            int r = h + (tid >> 5), c = tid & 31;
            P[r * PSTR + ((((c >> 2) ^ psw(r)) << 2)) + (c & 3)] = 0.f;
        }
        __syncthreads();

        // ------------- wave0: in-register diag Cholesky + z-panel solve -----
        if (tid < 32) {
            int l = tid;
            float a[32];
            float* prow = P + l * PSTR;
            int sw = psw(l);
            #pragma unroll
            for (int q = 0; q < 8; q++) {
                float4 t = *(float4*)(prow + ((q ^ sw) << 2));
                a[4*q+0] = t.x; a[4*q+1] = t.y; a[4*q+2] = t.z; a[4*q+3] = t.w;
            }
            float z = zsh[j0 + l];
            float dinv = 0.f;
            #pragma unroll
            for (int k = 0; k < 32; k++) {
                if (k < nb) {
                    float akk = __shfl(a[k], k, 64);
                    float lkk = sqrtf(akk);
                    float rinv = 1.f / lkk;
                    if (l == k) { dinv = rinv; llog += logf(lkk); }
                    a[k] = (l == k) ? lkk : a[k] * rinv;
                    #pragma unroll
                    for (int j = k + 1; j < 32; j++) {
                        float ajk = __shfl(a[k], j, 64);
                        a[j] -= a[k] * ajk;
                    }
                }
            }
            // forward solve for z[j0..j0+nb) using row l in registers
            #pragma unroll
            for (int k = 0; k < 32; k++) {
                if (k < nb) {
                    if (l == k) z *= dinv;
                    float zk = __shfl(z, k, 64);
                    if (l > k) z -= a[k] * zk;
                }
            }
            if (l < nb) zsh[j0 + l] = z;
            dinvbuf[l] = dinv;
            // store factored rows (zeros for l >= nb so trsm's fmas are inert)
            #pragma unroll
            for (int q = 0; q < 8; q++) {
                float4 t = (l < nb)
                    ? make_float4(a[4*q], a[4*q+1], a[4*q+2], a[4*q+3])
                    : make_float4(0.f, 0.f, 0.f, 0.f);
                *(float4*)(prow + ((q ^ sw) << 2)) = t;
            }
        }
        __syncthreads();

        // ------------- trsm rows (left-looking, per-thread) + z-update ------
        if (m > 0) {   // nb == 32 here
            for (int r = 32 + tid; r < h; r += 256) {
                float p[32];
                float* prow = P + r * PSTR;
                int sw = psw(r);
                #pragma unroll
                for (int q = 0; q < 8; q++) {
                    float4 t = *(float4*)(prow + ((q ^ sw) << 2));
                    p[4*q+0] = t.x; p[4*q+1] = t.y; p[4*q+2] = t.z; p[4*q+3] = t.w;
                }
                #pragma unroll
                for (int j = 0; j < 32; j++) {
                    float acc = p[j];
                    #pragma unroll
                    for (int q = 0; 4 * q < j; q++) {
                        const float4 t = *(const float4*)(P + j * PSTR + ((q ^ psw(j)) << 2));
                        if (4 * q + 0 < j) acc -= p[4*q+0] * t.x;
                        if (4 * q + 1 < j) acc -= p[4*q+1] * t.y;
                        if (4 * q + 2 < j) acc -= p[4*q+2] * t.z;
                        if (4 * q + 3 < j) acc -= p[4*q+3] * t.w;
                    }
                    p[j] = acc * dinvbuf[j];
                }
                float zu = 0.f;
                #pragma unroll
                for (int q = 0; q < 8; q++) {
                    float4 t = make_float4(p[4*q], p[4*q+1], p[4*q+2], p[4*q+3]);
                    *(float4*)(prow + ((q ^ sw) << 2)) = t;
                    float4 zz = *(const float4*)&zsh[j0 + 4 * q];
                    zu += p[4*q] * zz.x + p[4*q+1] * zz.y + p[4*q+2] * zz.z + p[4*q+3] * zz.w;
                }
                zsh[j0 + r] -= zu;
            }
        }
        __syncthreads();

        // ------------- syrk: trailing update, 8x8 register tiles ------------
        if (m > 0) {
            int T = (m + 7) >> 3;
            int ntiles = T * (T + 1) / 2;
            for (int e = tid; e < ntiles; e += 256) {
                int ti = (int)((sqrtf(8.f * (float)e + 1.f) - 1.f) * 0.5f);
                while ((ti + 1) * (ti + 2) / 2 <= e) ti++;
                while (ti * (ti + 1) / 2 > e) ti--;
                int tj = e - ti * (ti + 1) / 2;
                int oA[8], oB[8], sA[8], sB[8];
                #pragma unroll
                for (int a = 0; a < 8; a++) {
                    int ra = 32 + ti * 8 + a, rb = 32 + tj * 8 + a;
                    oA[a] = ra * PSTR; sA[a] = psw(ra);
                    oB[a] = rb * PSTR; sB[a] = psw(rb);
                }
                float acc[8][8];
                #pragma unroll
                for (int a = 0; a < 8; a++)
                    #pragma unroll
                    for (int c = 0; c < 8; c++) acc[a][c] = 0.f;
                #pragma unroll
                for (int qk = 0; qk < 8; qk++) {
                    float4 av[8], bv[8];
                    #pragma unroll
                    for (int a = 0; a < 8; a++)
                        av[a] = *(const float4*)(P + oA[a] + ((qk ^ sA[a]) << 2));
                    #pragma unroll
                    for (int c = 0; c < 8; c++)
                        bv[c] = *(const float4*)(P + oB[c] + ((qk ^ sB[c]) << 2));
                    #pragma unroll
                    for (int a = 0; a < 8; a++)
                        #pragma unroll
                        for (int c = 0; c < 8; c++)
                            acc[a][c] += av[a].x * bv[c].x + av[a].y * bv[c].y +
                                         av[a].z * bv[c].z + av[a].w * bv[c].w;
                }
                int ibase = j0 + 32 + ti * 8, jbase = j0 + 32 + tj * 8;
                #pragma unroll
                for (int a = 0; a < 8; a++) {
                    int i = ibase + a;
                    if (i < n) {
                        float* srow = Sb + (size_t)i * LDA;
                        #pragma unroll
                        for (int c = 0; c < 8; c++) {
                            int j = jbase + c;
                            if (j <= i) {
                                if (first) srow[j] = -acc[a][c];
                                else       srow[j] -= acc[a][c];
                            }
                        }
                    }
                }
            }
        }
        __syncthreads();
    }

    // ---------------- epilogue: quad + logdet reduce ----------------
    float q = 0.f;
    for (int i = tid; i < n; i += 256) { float zv = zsh[i]; q += zv * zv; }
    #pragma unroll
    for (int off = 32; off; off >>= 1) {
        q    += __shfl_down(q, off, 64);
        llog += __shfl_down(llog, off, 64);
    }
    int lane = tid & 63, wv = tid >> 6;
    if (lane == 0) { redbuf[wv] = q; redbuf[4 + wv] = llog; }
    __syncthreads();
    if (tid == 0) {
        float qt = redbuf[0] + redbuf[1] + redbuf[2] + redbuf[3];
        float ls = redbuf[4] + redbuf[5] + redbuf[6] + redbuf[7];
        out[b] = 0.5f * (qt + 2.f * ls + (float)n * LOG_2PI);
    }
}

// ---------------------------------------------------------------------------
// Launcher. ws: [0,1M) cov | [1M,2M) A | n_obs | obs_idx | rc | S (chunked)
// ---------------------------------------------------------------------------
extern "C" void kernel_launch(void* const* d_in, const int* in_sizes, int n_in,
                              void* d_out, int out_size, void* d_ws, size_t ws_size,
                              hipStream_t stream) {
    const float* x    = (const float*)d_in[0];
    const float* mu   = (const float*)d_in[1];
    const float* logd = (const float*)d_in[2];
    const float* lt   = (const float*)d_in[3];
    const int*   mask = (const int*)d_in[4];
    float* out = (float*)d_out;

    char* ws = (char*)d_ws;
    float* cov     = (float*)(ws);
    float* A       = (float*)(ws + 1048576);
    int*   n_obs   = (int*)  (ws + 2097152);
    int*   obs_idx = (int*)  (ws + 2098176);
    float* rc      = (float*)(ws + 2622464);
    float* S       = (float*)(ws + 3146752);

    size_t per = (size_t)LDA * LDA * 4;
    size_t avail = (ws_size > 3146752) ? (ws_size - 3146752) : 0;
    int chunk = (int)(avail / per);
    if (chunk > 256) chunk = 256;
    if (chunk < 1) chunk = 1;

    build_A<<<1024, 256, 0, stream>>>(logd, lt, A);
    dim3 g(16, 16);
    aat<<<g, 256, 0, stream>>>(A, cov);
    compact<<<256, 256, 0, stream>>>(x, mu, mask, obs_idx, n_obs, rc);

    for (int c0 = 0; c0 < 256; c0 += chunk) {
        int cn = (256 - c0 < chunk) ? (256 - c0) : chunk;
        chol_solve<<<cn, 256, 0, stream>>>(cov, rc, obs_idx, n_obs, S, out, c0);
    }
}